// Round 2
// baseline (789.940 us; speedup 1.0000x reference)
//
#include <hip/hip_runtime.h>
#include <hip/hip_bf16.h>

// EdgeAwareCritic: 3x GATv2 (H=2 heads, HID=128) + FiLM + MLP head, scalar output.
// All float tensors are fp32 per the reference; edge_index is int32.

// ---------------- CSR build ----------------
__global__ void hist_kernel(const int* __restrict__ dst, int* __restrict__ deg, int n) {
    int i = blockIdx.x * blockDim.x + threadIdx.x;
    if (i < n) atomicAdd(&deg[dst[i]], 1);
}

__global__ __launch_bounds__(1024) void scan_kernel(const int* __restrict__ deg,
                                                    int* __restrict__ rowp,
                                                    int* __restrict__ cur, int n) {
    __shared__ int sums[1024];
    const int t = threadIdx.x;
    const int PER = 20;                 // 1024*20 = 20480 >= 20000
    int base = t * PER;
    int local[PER];
    int run = 0;
#pragma unroll
    for (int i = 0; i < PER; ++i) {
        int v = (base + i < n) ? deg[base + i] : 0;
        local[i] = run; run += v;
    }
    sums[t] = run; __syncthreads();
    for (int off = 1; off < 1024; off <<= 1) {
        int v = (t >= off) ? sums[t - off] : 0;
        __syncthreads();
        sums[t] += v;
        __syncthreads();
    }
    int offs = (t > 0) ? sums[t - 1] : 0;
#pragma unroll
    for (int i = 0; i < PER; ++i) {
        int idx = base + i;
        if (idx < n) { int v = offs + local[i]; rowp[idx] = v; cur[idx] = v; }
    }
    if (t == 0) rowp[n] = sums[1023];
}

__global__ void scatter_kernel(const int* __restrict__ src, const int* __restrict__ dst,
                               int* __restrict__ cur, int* __restrict__ csrs,
                               int* __restrict__ csre, int n) {
    int i = blockIdx.x * blockDim.x + threadIdx.x;
    if (i < n) {
        int d = dst[i];
        int p = atomicAdd(&cur[d], 1);
        csrs[p] = src[i];
        csre[p] = i;
    }
}

// ---------------- tiled fp32 GEMM: C[M,N] = A[M,K] @ W[N,K]^T + b, opt relu ------
template <int BK, bool RELU>
__global__ __launch_bounds__(256) void gemm_kernel(const float* __restrict__ A,
                                                   const float* __restrict__ W,
                                                   const float* __restrict__ bp,
                                                   float* __restrict__ C,
                                                   int M, int N, int K) {
    __shared__ float As[BK][68];   // [k][row], stride 68 keeps float4 rows aligned, low conflicts
    __shared__ float Ws[BK][68];
    const int t = threadIdx.x;
    const int m0 = blockIdx.y * 64;
    const int n0 = blockIdx.x * 64;
    const int tx = t & 15, ty = t >> 4;
    float acc[4][4];
#pragma unroll
    for (int i = 0; i < 4; ++i)
#pragma unroll
        for (int j = 0; j < 4; ++j) acc[i][j] = 0.f;

    for (int k0 = 0; k0 < K; k0 += BK) {
        if (BK == 32) {
            const int r = t >> 3, cc = (t & 7) * 4;
#pragma unroll
            for (int half = 0; half < 2; ++half) {
                const int row = r + half * 32;
                const int arow = m0 + row;
                float4 av = (arow < M) ? *(const float4*)(A + (size_t)arow * K + k0 + cc)
                                       : make_float4(0.f, 0.f, 0.f, 0.f);
                As[cc + 0][row] = av.x; As[cc + 1][row] = av.y;
                As[cc + 2][row] = av.z; As[cc + 3][row] = av.w;
                float4 wv = *(const float4*)(W + (size_t)(n0 + row) * K + k0 + cc);
                Ws[cc + 0][row] = wv.x; Ws[cc + 1][row] = wv.y;
                Ws[cc + 2][row] = wv.z; Ws[cc + 3][row] = wv.w;
            }
        } else {  // BK == 16
            const int r = t >> 2, cc = (t & 3) * 4;
            const int arow = m0 + r;
            float4 av = (arow < M) ? *(const float4*)(A + (size_t)arow * K + k0 + cc)
                                   : make_float4(0.f, 0.f, 0.f, 0.f);
            As[cc + 0][r] = av.x; As[cc + 1][r] = av.y;
            As[cc + 2][r] = av.z; As[cc + 3][r] = av.w;
            float4 wv = *(const float4*)(W + (size_t)(n0 + r) * K + k0 + cc);
            Ws[cc + 0][r] = wv.x; Ws[cc + 1][r] = wv.y;
            Ws[cc + 2][r] = wv.z; Ws[cc + 3][r] = wv.w;
        }
        __syncthreads();
#pragma unroll
        for (int k = 0; k < BK; ++k) {
            float4 a4 = *(const float4*)&As[k][ty * 4];
            float4 b4 = *(const float4*)&Ws[k][tx * 4];
            float a_[4] = {a4.x, a4.y, a4.z, a4.w};
            float b_[4] = {b4.x, b4.y, b4.z, b4.w};
#pragma unroll
            for (int i = 0; i < 4; ++i)
#pragma unroll
                for (int j = 0; j < 4; ++j) acc[i][j] += a_[i] * b_[j];
        }
        __syncthreads();
    }
    float4 bj = *(const float4*)(bp + n0 + tx * 4);
    float bb[4] = {bj.x, bj.y, bj.z, bj.w};
#pragma unroll
    for (int i = 0; i < 4; ++i) {
        int row = m0 + ty * 4 + i;
        if (row < M) {
            float4 o;
            o.x = acc[i][0] + bb[0]; o.y = acc[i][1] + bb[1];
            o.z = acc[i][2] + bb[2]; o.w = acc[i][3] + bb[3];
            if (RELU) {
                o.x = fmaxf(o.x, 0.f); o.y = fmaxf(o.y, 0.f);
                o.z = fmaxf(o.z, 0.f); o.w = fmaxf(o.w, 0.f);
            }
            *(float4*)(C + (size_t)row * N + n0 + tx * 4) = o;
        }
    }
}

// ---------------- GATv2 edge kernel: one wave per dst node, online softmax -------
// xl/xr: [N,256] f32 (feature idx = h*128+c). out: relu(mean_heads + bias) [N,128].
__global__ __launch_bounds__(256) void gat_kernel(
    const float* __restrict__ xl, const float* __restrict__ xr,
    const int* __restrict__ rowp, const int* __restrict__ csrs, const int* __restrict__ csre,
    const float* __restrict__ ea, const float* __restrict__ We,
    const float* __restrict__ att, const float* __restrict__ bias,
    float* __restrict__ hout, int nnodes) {
    __shared__ float WeT[16][256];   // WeT[k][f] = We[f][k]
    const int t = threadIdx.x;
    {
        const float4* wp = (const float4*)(We + t * 16);
#pragma unroll
        for (int q = 0; q < 4; ++q) {
            float4 u = wp[q];
            WeT[q * 4 + 0][t] = u.x; WeT[q * 4 + 1][t] = u.y;
            WeT[q * 4 + 2][t] = u.z; WeT[q * 4 + 3][t] = u.w;
        }
    }
    __syncthreads();
    const int l = t & 63;                       // lane: owns features 4l..4l+3 (head = l>=32)
    const int node = blockIdx.x * 4 + (t >> 6);
    if (node >= nnodes) return;
    const int rs = rowp[node], re = rowp[node + 1];
    const float4 xr4 = *(const float4*)(xr + (size_t)node * 256 + 4 * l);
    const float4 att4 = *(const float4*)(att + 4 * l);
    float mrun = -INFINITY, drun = 0.f;
    float ax = 0.f, ay = 0.f, az = 0.f, aw = 0.f;
    for (int i = rs; i < re; ++i) {
        const int s = csrs[i];
        const int e = csre[i];
        const float4 xl4 = *(const float4*)(xl + (size_t)s * 256 + 4 * l);
        const float4* ep = (const float4*)(ea + (size_t)e * 16);
        float eav[16];
#pragma unroll
        for (int q = 0; q < 4; ++q) {
            float4 u = ep[q];
            eav[q * 4 + 0] = u.x; eav[q * 4 + 1] = u.y;
            eav[q * 4 + 2] = u.z; eav[q * 4 + 3] = u.w;
        }
        float ex = 0.f, ey = 0.f, ez = 0.f, ew = 0.f;
#pragma unroll
        for (int k = 0; k < 16; ++k) {
            float4 wv = *(const float4*)&WeT[k][4 * l];
            ex += eav[k] * wv.x; ey += eav[k] * wv.y;
            ez += eav[k] * wv.z; ew += eav[k] * wv.w;
        }
        float sx = xl4.x + xr4.x + ex, sy = xl4.y + xr4.y + ey;
        float sz = xl4.z + xr4.z + ez, sw = xl4.w + xr4.w + ew;
        sx = sx > 0.f ? sx : 0.2f * sx;  sy = sy > 0.f ? sy : 0.2f * sy;
        sz = sz > 0.f ? sz : 0.2f * sz;  sw = sw > 0.f ? sw : 0.2f * sw;
        float tv = sx * att4.x + sy * att4.y + sz * att4.z + sw * att4.w;
        // per-head reduce (offsets stay inside each 32-lane half)
        tv += __shfl_xor(tv, 1);  tv += __shfl_xor(tv, 2);  tv += __shfl_xor(tv, 4);
        tv += __shfl_xor(tv, 8);  tv += __shfl_xor(tv, 16);
        float nm = fmaxf(mrun, tv);
        float p  = __expf(tv - nm);
        float sc = __expf(mrun - nm);    // first edge: exp(-inf)=0
        drun = drun * sc + p;
        ax = ax * sc + p * xl4.x; ay = ay * sc + p * xl4.y;
        az = az * sc + p * xl4.z; aw = aw * sc + p * xl4.w;
        mrun = nm;
    }
    float ox, oy, oz, ow;
    if (re > rs) {
        float inv = 1.f / drun;
        ox = ax * inv; oy = ay * inv; oz = az * inv; ow = aw * inv;
    } else { ox = oy = oz = ow = 0.f; }   // isolated node: segment_sum over empty = 0
    // mean over heads: lane l (head0, chans 4l..) pairs with lane l^32 (head1, same chans)
    ox += __shfl_xor(ox, 32); oy += __shfl_xor(oy, 32);
    oz += __shfl_xor(oz, 32); ow += __shfl_xor(ow, 32);
    if (l < 32) {
        float4 bu = *(const float4*)(bias + 4 * l);
        float4 o;
        o.x = fmaxf(0.5f * ox + bu.x, 0.f);
        o.y = fmaxf(0.5f * oy + bu.y, 0.f);
        o.z = fmaxf(0.5f * oz + bu.z, 0.f);
        o.w = fmaxf(0.5f * ow + bu.w, 0.f);
        *(float4*)(hout + (size_t)node * 128 + 4 * l) = o;
    }
}

// ---------------- FiLM: h = gm*h + bm (elementwise) ----------------
__global__ void film_kernel(float4* __restrict__ h, const float4* __restrict__ gm,
                            const float4* __restrict__ bm, int n4) {
    for (int i = blockIdx.x * blockDim.x + threadIdx.x; i < n4; i += gridDim.x * blockDim.x) {
        float4 hv = h[i], g = gm[i], b = bm[i];
        hv.x = g.x * hv.x + b.x; hv.y = g.y * hv.y + b.y;
        hv.z = g.z * hv.z + b.z; hv.w = g.w * hv.w + b.w;
        h[i] = hv;
    }
}

// ---------------- column sum of h[rows,128] -> col[128] ----------------
__global__ __launch_bounds__(256) void colsum_kernel(const float* __restrict__ h,
                                                     float* __restrict__ col, int rows) {
    int c = threadIdx.x & 127;
    int r = blockIdx.x * 2 + (threadIdx.x >> 7);
    float s = 0.f;
    for (; r < rows; r += gridDim.x * 2) s += h[(size_t)r * 128 + c];
    atomicAdd(&col[c], s);
}

// ---------------- out = dot(col/N, q2_W) + q2_b ----------------
__global__ __launch_bounds__(128) void final_kernel(const float* __restrict__ col,
                                                    const float* __restrict__ q2w,
                                                    const float* __restrict__ q2b,
                                                    float* __restrict__ out, float invn) {
    __shared__ float red[128];
    int t = threadIdx.x;
    red[t] = col[t] * invn * q2w[t];
    __syncthreads();
    for (int off = 64; off > 0; off >>= 1) {
        if (t < off) red[t] += red[t + off];
        __syncthreads();
    }
    if (t == 0) out[0] = red[0] + q2b[0];
}

extern "C" void kernel_launch(void* const* d_in, const int* in_sizes, int n_in,
                              void* d_out, int out_size, void* d_ws, size_t ws_size,
                              hipStream_t stream) {
    const int N = in_sizes[0] / 128;   // 20000
    const int E = in_sizes[1] / 2;     // 320000

    typedef const float* fp;
    fp x      = (fp)d_in[0];
    const int* ei = (const int*)d_in[1];
    fp ea     = (fp)d_in[2];
    fp action = (fp)d_in[3];
    fp inp_W  = (fp)d_in[4];
    fp inp_b  = (fp)d_in[5];
    // GAT layers: s1 @6, s2 @13, sa @20 — [Wl, bl, Wr, br, We, att, bias]
    fp ap_W = (fp)d_in[27], ap_b = (fp)d_in[28];
    fp g_W  = (fp)d_in[29], g_b  = (fp)d_in[30];
    fp be_W = (fp)d_in[31], be_b = (fp)d_in[32];
    fp q1_W = (fp)d_in[33], q1_b = (fp)d_in[34];
    fp q2_W = (fp)d_in[35], q2_b = (fp)d_in[36];

    // workspace layout (256B aligned)
    char* base = (char*)d_ws;
    size_t off = 0;
    auto alloc = [&](size_t bytes) { char* p = base + off; off = (off + bytes + 255) & ~(size_t)255; return p; };
    float* h    = (float*)alloc((size_t)N * 128 * 4);
    float* xlb  = (float*)alloc((size_t)N * 256 * 4);
    float* xrb  = (float*)alloc((size_t)N * 256 * 4);
    float* col  = (float*)alloc(128 * 4);
    int* deg    = (int*)alloc((size_t)N * 4);
    int* rowp   = (int*)alloc((size_t)(N + 1) * 4);
    int* cur    = (int*)alloc((size_t)N * 4);
    int* csrs   = (int*)alloc((size_t)E * 4);
    int* csre   = (int*)alloc((size_t)E * 4);
    float* abuf = xrb + (size_t)N * 128;   // reuse: [N,128] sub-buffer, free at FiLM time
    (void)ws_size; (void)n_in; (void)out_size;

    const int* src = ei;
    const int* dst = ei + E;

    // CSR build (reused by all 3 GAT layers)
    hipMemsetAsync(deg, 0, (size_t)N * 4, stream);
    hist_kernel<<<(E + 255) / 256, 256, 0, stream>>>(dst, deg, E);
    scan_kernel<<<1, 1024, 0, stream>>>(deg, rowp, cur, N);
    scatter_kernel<<<(E + 255) / 256, 256, 0, stream>>>(src, dst, cur, csrs, csre, E);

    const dim3 g128(128 / 64, (N + 63) / 64);
    const dim3 g256(256 / 64, (N + 63) / 64);

    // h0 = relu(x @ inp_W^T + inp_b)
    gemm_kernel<32, true><<<g128, 256, 0, stream>>>(x, inp_W, inp_b, h, N, 128, 128);

    // s1, s2
    for (int L = 0; L < 2; ++L) {
        int b = 6 + 7 * L;
        fp Wl = (fp)d_in[b], bl = (fp)d_in[b + 1];
        fp Wr = (fp)d_in[b + 2], br = (fp)d_in[b + 3];
        fp We = (fp)d_in[b + 4], at = (fp)d_in[b + 5], bi = (fp)d_in[b + 6];
        gemm_kernel<32, false><<<g256, 256, 0, stream>>>(h, Wl, bl, xlb, N, 256, 128);
        gemm_kernel<32, false><<<g256, 256, 0, stream>>>(h, Wr, br, xrb, N, 256, 128);
        gat_kernel<<<(N + 3) / 4, 256, 0, stream>>>(xlb, xrb, rowp, csrs, csre, ea, We, at, bi, h, N);
    }

    // FiLM: a = relu(action@ap^T+ap_b); h = (a@g^T+g_b)*h + (a@be^T+be_b)
    gemm_kernel<16, true><<<g128, 256, 0, stream>>>(action, ap_W, ap_b, abuf, N, 128, 16);
    gemm_kernel<32, false><<<g128, 256, 0, stream>>>(abuf, g_W, g_b, xlb, N, 128, 128);
    gemm_kernel<32, false><<<g128, 256, 0, stream>>>(abuf, be_W, be_b, xlb + (size_t)N * 128, N, 128, 128);
    film_kernel<<<1024, 256, 0, stream>>>((float4*)h, (const float4*)xlb,
                                          (const float4*)(xlb + (size_t)N * 128), N * 128 / 4);

    // sa
    {
        int b = 20;
        fp Wl = (fp)d_in[b], bl = (fp)d_in[b + 1];
        fp Wr = (fp)d_in[b + 2], br = (fp)d_in[b + 3];
        fp We = (fp)d_in[b + 4], at = (fp)d_in[b + 5], bi = (fp)d_in[b + 6];
        gemm_kernel<32, false><<<g256, 256, 0, stream>>>(h, Wl, bl, xlb, N, 256, 128);
        gemm_kernel<32, false><<<g256, 256, 0, stream>>>(h, Wr, br, xrb, N, 256, 128);
        gat_kernel<<<(N + 3) / 4, 256, 0, stream>>>(xlb, xrb, rowp, csrs, csre, ea, We, at, bi, h, N);
    }

    // q1 + scalar head: mean_n(relu(h@q1^T+b) @ q2^T + q2_b) via column-sum trick
    gemm_kernel<32, true><<<g128, 256, 0, stream>>>(h, q1_W, q1_b, xlb, N, 128, 128);
    hipMemsetAsync(col, 0, 128 * 4, stream);
    colsum_kernel<<<256, 256, 0, stream>>>(xlb, col, N);
    final_kernel<<<1, 128, 0, stream>>>(col, q2_W, q2_b, (float*)d_out, 1.0f / (float)N);
}